// Round 1
// baseline (876.945 us; speedup 1.0000x reference)
//
#include <hip/hip_runtime.h>
#include <cstddef>

#define BB 64
#define NN 1024
#define CC 256
#define KK 512
#define TT 64
#define NPAIR 128

// ---------------- ws layout (float words) ----------------
// feat    : 0          size B*K*C   = 8388608
// normF   : 8388608    size 32768
// centk   : 8421376    size B*K*4   = 131072   (x,y,z,|c|^2)
// sbuf    : 8552448    size 65536   (T*2*K)
// topidx  : 8617984    size 32768   (int)
// neff    : 8650752    size 64      (int)
// corr    : 8650816    size 65536   (int)
// gmask   : 8716352    size NPAIR*K*16 = 1048576 (uint)
// total 9764928 words = 39.06 MB

// ===================== stage 1: selection =====================
__global__ __launch_bounds__(512) void sel_kernel(
    const float* __restrict__ attn, const float* __restrict__ cents,
    const float* __restrict__ sas, const int* __restrict__ num_rt,
    int* __restrict__ topidx, int* __restrict__ neff, float* __restrict__ centk)
{
    __shared__ unsigned long long keys[1024];
    const int b = blockIdx.x, tid = threadIdx.x;
    const int nr = num_rt[b];
    for (int i = tid; i < 1024; i += 512) {
        float a = (i < nr) ? attn[b * NN + i] : -1e9f;
        unsigned u = __float_as_uint(a);
        u = (u & 0x80000000u) ? ~u : (u | 0x80000000u);
        keys[i] = ((unsigned long long)u << 32) | (unsigned)(0xFFFFFFFFu - (unsigned)i);
    }
    __syncthreads();
    // bitonic sort, descending; ties -> smaller index first (stable top_k semantics)
    for (int k = 2; k <= 1024; k <<= 1) {
        for (int j = k >> 1; j > 0; j >>= 1) {
            int i = ((tid & ~(j - 1)) << 1) | (tid & (j - 1));
            int p = i | j;
            unsigned long long a = keys[i], c = keys[p];
            bool up = (i & k) == 0;                  // descending block
            if (up ? (a < c) : (a > c)) { keys[i] = c; keys[p] = a; }
            __syncthreads();
        }
    }
    {
        unsigned long long key = keys[tid];
        int idx = (int)(~(unsigned)key);             // low32 = ~i
        float x = cents[(b * NN + idx) * 3 + 0];
        float y = cents[(b * NN + idx) * 3 + 1];
        float z = cents[(b * NN + idx) * 3 + 2];
        if (idx < nr) {
            float sc = sas[b * 4 + 3];
            x = x * sc + sas[b * 4 + 0];
            y = y * sc + sas[b * 4 + 1];
            z = z * sc + sas[b * 4 + 2];
        }
        float nc = x * x + y * y + z * z;
        ((float4*)centk)[b * KK + tid] = make_float4(x, y, z, nc);
        topidx[b * KK + tid] = idx;
    }
    if (tid == 0) neff[b] = (nr < KK) ? nr : KK;
}

// ===================== stage 2: feat = rt_k @ W_in + b_in =====================
__global__ __launch_bounds__(256) void feat_kernel(
    const float* __restrict__ rt, const int* __restrict__ topidx,
    const float* __restrict__ Win, const float* __restrict__ bin,
    float* __restrict__ feat)
{
    __shared__ __align__(16) float As[16][68];   // [kc][m]
    __shared__ __align__(16) float Bs[16][68];   // [kc][n]
    __shared__ int tix[64];
    const int mtile = blockIdx.x;     // 512 tiles of 64 rows (row = b*512+k)
    const int ntile = blockIdx.y * 64;
    const int tid = threadIdx.x;
    const int tx = tid & 15, ty = tid >> 4;
    if (tid < 64) tix[tid] = topidx[mtile * 64 + tid];
    float acc[4][4] = {};
    for (int k0 = 0; k0 < CC; k0 += 16) {
        __syncthreads();
        for (int e = tid; e < 1024; e += 256) {
            int row = e >> 4, kc = e & 15;
            int r = mtile * 64 + row;
            int bb2 = r >> 9;
            As[kc][row] = rt[((size_t)bb2 * NN + tix[row]) * CC + k0 + kc];
            Bs[kc & 15][ (e & 1023) >= 0 ? 0 : 0] = 0.f; // placeholder avoided below
        }
        // B tile load (separate loop for clean indexing)
        for (int e = tid; e < 1024; e += 256) {
            int kc = e >> 6, nn2 = e & 63;
            Bs[kc][nn2] = Win[(k0 + kc) * CC + ntile + nn2];
        }
        __syncthreads();
        #pragma unroll
        for (int kc = 0; kc < 16; kc++) {
            float4 av = *(const float4*)&As[kc][ty * 4];
            float4 bv = *(const float4*)&Bs[kc][tx * 4];
            float a4[4] = {av.x, av.y, av.z, av.w};
            float b4[4] = {bv.x, bv.y, bv.z, bv.w};
            #pragma unroll
            for (int i = 0; i < 4; i++)
                #pragma unroll
                for (int j = 0; j < 4; j++)
                    acc[i][j] += a4[i] * b4[j];
        }
    }
    for (int i = 0; i < 4; i++) {
        int r = mtile * 64 + ty * 4 + i;
        float4 o;
        o.x = acc[i][0] + bin[ntile + tx * 4 + 0];
        o.y = acc[i][1] + bin[ntile + tx * 4 + 1];
        o.z = acc[i][2] + bin[ntile + tx * 4 + 2];
        o.w = acc[i][3] + bin[ntile + tx * 4 + 3];
        *(float4*)&feat[(size_t)r * CC + ntile + tx * 4] = o;
    }
}

// ===================== stage 2b: row norms =====================
__global__ __launch_bounds__(256) void norm_kernel(
    const float* __restrict__ feat, float* __restrict__ normF)
{
    int r = blockIdx.x * 4 + (threadIdx.x >> 6);
    int lane = threadIdx.x & 63;
    const float* p = feat + (size_t)r * CC;
    float s = 0.f;
    for (int c = lane; c < CC; c += 64) { float v = p[c]; s += v * v; }
    for (int off = 32; off; off >>= 1) s += __shfl_down(s, off);
    if (lane == 0) normF[r] = s;
}

// ===================== stage 3: argmin + cos =====================
__global__ __launch_bounds__(256) void argmin_kernel(
    const float* __restrict__ feat, const float* __restrict__ normF,
    const int* __restrict__ anc, const int* __restrict__ pos, const int* __restrict__ neg,
    int* __restrict__ corr, float* __restrict__ sbuf)
{
    const int kt = blockIdx.x;          // 0..7  (k tile of 64)
    const int nn2 = blockIdx.y;         // 0..1
    const int t = blockIdx.z;           // 0..63
    const int a = anc[t];
    const int bb2 = (nn2 == 0) ? pos[t] : neg[t];
    const float* Af = feat + ((size_t)a * KK + kt * 64) * CC;
    const float* Bf = feat + (size_t)bb2 * KK * CC;
    __shared__ __align__(16) float As[16][68];   // [kc][k-row]
    __shared__ __align__(16) float Bs[16][68];   // [kc][l-row]
    __shared__ float rv[64][16];
    __shared__ int   rl[64][16];
    __shared__ float rd[64][16];
    const int tid = threadIdx.x;
    const int tx = tid & 15, ty = tid >> 4;
    float bestv[4]; int bestl[4]; float bestd[4];
    #pragma unroll
    for (int i = 0; i < 4; i++) { bestv[i] = INFINITY; bestl[i] = 0; bestd[i] = 0.f; }

    for (int lt = 0; lt < KK; lt += 64) {
        float acc[4][4] = {};
        for (int k0 = 0; k0 < CC; k0 += 16) {
            __syncthreads();
            for (int e = tid; e < 1024; e += 256) {
                int row = e >> 4, kc = e & 15;
                As[kc][row] = Af[row * CC + k0 + kc];
                Bs[kc][row] = Bf[(size_t)(lt + row) * CC + k0 + kc];
            }
            __syncthreads();
            #pragma unroll
            for (int kc = 0; kc < 16; kc++) {
                float4 av = *(const float4*)&As[kc][ty * 4];
                float4 bv = *(const float4*)&Bs[kc][tx * 4];
                float a4[4] = {av.x, av.y, av.z, av.w};
                float b4[4] = {bv.x, bv.y, bv.z, bv.w};
                #pragma unroll
                for (int i = 0; i < 4; i++)
                    #pragma unroll
                    for (int j = 0; j < 4; j++)
                        acc[i][j] += a4[i] * b4[j];
            }
        }
        #pragma unroll
        for (int j = 0; j < 4; j++) {
            int l = lt + tx * 4 + j;
            float nb = normF[(size_t)bb2 * KK + l];
            #pragma unroll
            for (int i = 0; i < 4; i++) {
                float v = nb - 2.f * acc[i][j];
                if (v < bestv[i]) { bestv[i] = v; bestl[i] = l; bestd[i] = acc[i][j]; }
            }
        }
    }
    __syncthreads();
    #pragma unroll
    for (int i = 0; i < 4; i++) {
        rv[ty * 4 + i][tx] = bestv[i];
        rl[ty * 4 + i][tx] = bestl[i];
        rd[ty * 4 + i][tx] = bestd[i];
    }
    __syncthreads();
    if (tid < 64) {
        int m = tid;
        float bv = rv[m][0]; int bl = rl[m][0]; float bd = rd[m][0];
        for (int x = 1; x < 16; x++) {
            float v = rv[m][x]; int l = rl[m][x];
            if (v < bv || (v == bv && l < bl)) { bv = v; bl = l; bd = rd[m][x]; }
        }
        int kg = kt * 64 + m;
        float na = normF[(size_t)a * KK + kg];
        float nb = normF[(size_t)bb2 * KK + bl];
        float cosv = bd / (sqrtf(na) * sqrtf(nb) + 1e-8f);
        int off = (t * 2 + nn2) * KK + kg;
        corr[off] = bl;
        sbuf[off] = fmaxf(cosv, 0.f);
    }
}

// ===================== stage 4: geo bitmask =====================
__global__ __launch_bounds__(256) void geo_kernel(
    const float* __restrict__ centk, const int* __restrict__ corr,
    const int* __restrict__ neff,
    const int* __restrict__ anc, const int* __restrict__ pos, const int* __restrict__ neg,
    unsigned* __restrict__ gmask)
{
    const int kt = blockIdx.x;          // 0..1 (256 rows each)
    const int nn2 = blockIdx.y;
    const int t = blockIdx.z;
    const int a = anc[t];
    const int bb2 = (nn2 == 0) ? pos[t] : neg[t];
    const int nea = neff[a], neb = neff[bb2];
    const int pair = t * 2 + nn2;
    __shared__ __align__(16) float4 ca[512], cq[512];
    for (int i = threadIdx.x; i < KK; i += 256) {
        ca[i] = ((const float4*)centk)[a * KK + i];
        int c = corr[pair * KK + i];
        cq[i] = ((const float4*)centk)[bb2 * KK + c];
    }
    __syncthreads();
    const int k = kt * 256 + threadIdx.x;
    float4 pk = ca[k], qk = cq[k];
    bool rowm = k < nea;
    unsigned* out = gmask + ((size_t)pair * KK + k) * 16;
    for (int w = 0; w < 16; w++) {
        unsigned word = 0;
        #pragma unroll
        for (int bi = 0; bi < 32; bi++) {
            int l = w * 32 + bi;
            float4 pl = ca[l], ql = cq[l];
            float dp2 = pk.w + pl.w - 2.f * (pk.x * pl.x + pk.y * pl.y + pk.z * pl.z);
            float dp = sqrtf(fmaxf(dp2, 0.f) + 1e-12f);
            float dq2 = qk.w + ql.w - 2.f * (qk.x * ql.x + qk.y * ql.y + qk.z * ql.z);
            float dq = sqrtf(fmaxf(dq2, 0.f) + 1e-12f);
            bool g = (fabsf(dp - dq) < 0.5f) && rowm && (l < neb) && (l != k);
            word |= (g ? (1u << bi) : 0u);
        }
        out[w] = word;
    }
}

// ===================== stage 5: power iteration + sort + MLP =====================
__global__ __launch_bounds__(256) void power_kernel(
    const unsigned* __restrict__ gmask, const float* __restrict__ sbuf,
    const float* __restrict__ W1, const float* __restrict__ b1,
    const float* __restrict__ W2, const float* __restrict__ b2,
    float* __restrict__ out)
{
    const int pair = blockIdx.x;
    const int tid = threadIdx.x;
    const int k0 = tid, k1 = tid + 256;
    __shared__ __align__(16) float u[512];
    __shared__ float red[4];
    __shared__ float ev[512];
    unsigned m0[16], m1[16];
    const unsigned* g0 = gmask + ((size_t)pair * KK + k0) * 16;
    const unsigned* g1 = gmask + ((size_t)pair * KK + k1) * 16;
    #pragma unroll
    for (int w = 0; w < 16; w++) { m0[w] = g0[w]; m1[w] = g1[w]; }
    float s0 = sbuf[pair * KK + k0], s1 = sbuf[pair * KK + k1];
    float v0 = 0.044194173824159216f, v1 = v0;   // 1/sqrt(512)
    for (int it = 0; it < 20; it++) {
        u[k0] = s0 * v0; u[k1] = s1 * v1;
        __syncthreads();
        float acc0 = 0.f, acc1 = 0.f;
        #pragma unroll
        for (int w = 0; w < 16; w++) {
            unsigned ma = m0[w], mb = m1[w];
            #pragma unroll
            for (int q = 0; q < 8; q++) {
                float4 uu = *(const float4*)&u[w * 32 + q * 4];
                int base = q * 4;
                if (ma & (1u << (base + 0))) acc0 += uu.x;
                if (ma & (1u << (base + 1))) acc0 += uu.y;
                if (ma & (1u << (base + 2))) acc0 += uu.z;
                if (ma & (1u << (base + 3))) acc0 += uu.w;
                if (mb & (1u << (base + 0))) acc1 += uu.x;
                if (mb & (1u << (base + 1))) acc1 += uu.y;
                if (mb & (1u << (base + 2))) acc1 += uu.z;
                if (mb & (1u << (base + 3))) acc1 += uu.w;
            }
        }
        float w0 = s0 * acc0, w1 = s1 * acc1;
        float t2 = w0 * w0 + w1 * w1;
        for (int off = 32; off; off >>= 1) t2 += __shfl_down(t2, off);
        if ((tid & 63) == 0) red[tid >> 6] = t2;
        __syncthreads();
        float tot = red[0] + red[1] + red[2] + red[3];
        float inv = 1.f / (sqrtf(tot) + 1e-8f);
        v0 = w0 * inv; v1 = w1 * inv;
        __syncthreads();
    }
    ev[k0] = v0; ev[k1] = v1;
    __syncthreads();
    // bitonic sort 512 descending with 256 threads
    for (int kk = 2; kk <= 512; kk <<= 1) {
        for (int j = kk >> 1; j; j >>= 1) {
            int i = ((tid & ~(j - 1)) << 1) | (tid & (j - 1));
            int p = i | j;
            float x = ev[i], y = ev[p];
            bool up = (i & kk) == 0;
            if (up ? (x < y) : (x > y)) { ev[i] = y; ev[p] = x; }
            __syncthreads();
        }
    }
    // MLP: h = relu(eig @ W1 + b1); score = sigmoid(h @ W2 + b2)
    float h0 = b1[k0], h1 = b1[k1];
    #pragma unroll 8
    for (int kk = 0; kk < KK; kk++) {
        float e = ev[kk];
        h0 += e * W1[(size_t)kk * KK + k0];
        h1 += e * W1[(size_t)kk * KK + k1];
    }
    h0 = fmaxf(h0, 0.f); h1 = fmaxf(h1, 0.f);
    float term = h0 * W2[k0] + h1 * W2[k1];
    for (int off = 32; off; off >>= 1) term += __shfl_down(term, off);
    __syncthreads();   // red reuse safety
    if ((tid & 63) == 0) red[tid >> 6] = term;
    __syncthreads();
    if (tid == 0) {
        float sc = red[0] + red[1] + red[2] + red[3] + b2[0];
        out[pair] = 1.f / (1.f + expf(-sc));
        out[NPAIR + pair] = (pair & 1) ? 0.f : 1.f;   // targets
    }
}

extern "C" void kernel_launch(void* const* d_in, const int* in_sizes, int n_in,
                              void* d_out, int out_size, void* d_ws, size_t ws_size,
                              hipStream_t stream) {
    (void)in_sizes; (void)n_in; (void)out_size; (void)ws_size;
    const float* rt    = (const float*)d_in[0];
    const float* cents = (const float*)d_in[1];
    const float* attn  = (const float*)d_in[2];
    const float* sas   = (const float*)d_in[3];
    const int* num_rt  = (const int*)d_in[4];
    const int* anc     = (const int*)d_in[5];
    const int* pos     = (const int*)d_in[6];
    const int* neg     = (const int*)d_in[7];
    const float* Win   = (const float*)d_in[8];
    const float* bin   = (const float*)d_in[9];
    const float* W1    = (const float*)d_in[10];
    const float* b1    = (const float*)d_in[11];
    const float* W2    = (const float*)d_in[12];
    const float* b2    = (const float*)d_in[13];

    float* ws = (float*)d_ws;
    float* feat  = ws;
    float* normF = ws + 8388608;
    float* centk = ws + 8421376;
    float* sbuf  = ws + 8552448;
    int* topidx  = (int*)(ws + 8617984);
    int* neffp   = (int*)(ws + 8650752);
    int* corr    = (int*)(ws + 8650816);
    unsigned* gmask = (unsigned*)(ws + 8716352);
    float* out = (float*)d_out;

    sel_kernel<<<64, 512, 0, stream>>>(attn, cents, sas, num_rt, topidx, neffp, centk);
    feat_kernel<<<dim3(512, 4), 256, 0, stream>>>(rt, topidx, Win, bin, feat);
    norm_kernel<<<8192, 256, 0, stream>>>(feat, normF);
    argmin_kernel<<<dim3(8, 2, 64), 256, 0, stream>>>(feat, normF, anc, pos, neg, corr, sbuf);
    geo_kernel<<<dim3(2, 2, 64), 256, 0, stream>>>(centk, corr, neffp, anc, pos, neg, gmask);
    power_kernel<<<128, 256, 0, stream>>>(gmask, sbuf, W1, b1, W2, b2, out);
}

// Round 2
// 869.486 us; speedup vs baseline: 1.0086x; 1.0086x over previous
//
#include <hip/hip_runtime.h>
#include <cstddef>

#define BB 64
#define NN 1024
#define CC 256
#define KK 512
#define TT 64
#define NPAIR 128

typedef _Float16 h8 __attribute__((ext_vector_type(8)));
typedef _Float16 h4 __attribute__((ext_vector_type(4)));
typedef float f4 __attribute__((ext_vector_type(4)));

// ---------------- ws layout (float words) ----------------
// feath   : 0          size 4194304  (8388608 f16: 32768 x 256 hi)
// featl   : 4194304    size 4194304  (lo plane)
// normF   : 8388608    size 32768
// centk   : 8421376    size B*K*4   = 131072   (x,y,z,|c|^2)
// sbuf    : 8552448    size 65536   (T*2*K)
// topidx  : 8617984    size 32768   (int)
// neff    : 8650752    size 64      (int)
// corr    : 8650816    size 65536   (int)
// gmask   : 8716352    size NPAIR*K*16 = 1048576 (uint)
//   partials alias the gmask region (consumed by argmin_fin BEFORE geo writes):
//   partv = gmask+0 (262144), partl = +262144, partd = +524288
// total 9764928 words = 39.06 MB (same as round 0)

// ===================== stage 1: selection =====================
__global__ __launch_bounds__(512) void sel_kernel(
    const float* __restrict__ attn, const float* __restrict__ cents,
    const float* __restrict__ sas, const int* __restrict__ num_rt,
    int* __restrict__ topidx, int* __restrict__ neff, float* __restrict__ centk)
{
    __shared__ unsigned long long keys[1024];
    const int b = blockIdx.x, tid = threadIdx.x;
    const int nr = num_rt[b];
    for (int i = tid; i < 1024; i += 512) {
        float a = (i < nr) ? attn[b * NN + i] : -1e9f;
        unsigned u = __float_as_uint(a);
        u = (u & 0x80000000u) ? ~u : (u | 0x80000000u);
        keys[i] = ((unsigned long long)u << 32) | (unsigned)(0xFFFFFFFFu - (unsigned)i);
    }
    __syncthreads();
    for (int k = 2; k <= 1024; k <<= 1) {
        for (int j = k >> 1; j > 0; j >>= 1) {
            int i = ((tid & ~(j - 1)) << 1) | (tid & (j - 1));
            int p = i | j;
            unsigned long long a = keys[i], c = keys[p];
            bool up = (i & k) == 0;
            if (up ? (a < c) : (a > c)) { keys[i] = c; keys[p] = a; }
            __syncthreads();
        }
    }
    {
        unsigned long long key = keys[tid];
        int idx = (int)(~(unsigned)key);
        float x = cents[(b * NN + idx) * 3 + 0];
        float y = cents[(b * NN + idx) * 3 + 1];
        float z = cents[(b * NN + idx) * 3 + 2];
        if (idx < nr) {
            float sc = sas[b * 4 + 3];
            x = x * sc + sas[b * 4 + 0];
            y = y * sc + sas[b * 4 + 1];
            z = z * sc + sas[b * 4 + 2];
        }
        float nc = x * x + y * y + z * z;
        ((float4*)centk)[b * KK + tid] = make_float4(x, y, z, nc);
        topidx[b * KK + tid] = idx;
    }
    if (tid == 0) neff[b] = (nr < KK) ? nr : KK;
}

// ===================== stage 2: feat = rt_k @ W_in + b_in (-> f16 hi/lo planes) ==
__global__ __launch_bounds__(256) void feat_kernel(
    const float* __restrict__ rt, const int* __restrict__ topidx,
    const float* __restrict__ Win, const float* __restrict__ bin,
    _Float16* __restrict__ feath, _Float16* __restrict__ featl)
{
    __shared__ __align__(16) float As[16][68];
    __shared__ __align__(16) float Bs[16][68];
    __shared__ int tix[64];
    const int mtile = blockIdx.x;
    const int ntile = blockIdx.y * 64;
    const int tid = threadIdx.x;
    const int tx = tid & 15, ty = tid >> 4;
    if (tid < 64) tix[tid] = topidx[mtile * 64 + tid];
    float acc[4][4] = {};
    for (int k0 = 0; k0 < CC; k0 += 16) {
        __syncthreads();
        for (int e = tid; e < 1024; e += 256) {
            int row = e >> 4, kc = e & 15;
            int r = mtile * 64 + row;
            int bb2 = r >> 9;
            As[kc][row] = rt[((size_t)bb2 * NN + tix[row]) * CC + k0 + kc];
        }
        for (int e = tid; e < 1024; e += 256) {
            int kc = e >> 6, nn2 = e & 63;
            Bs[kc][nn2] = Win[(k0 + kc) * CC + ntile + nn2];
        }
        __syncthreads();
        #pragma unroll
        for (int kc = 0; kc < 16; kc++) {
            float4 av = *(const float4*)&As[kc][ty * 4];
            float4 bv = *(const float4*)&Bs[kc][tx * 4];
            float a4[4] = {av.x, av.y, av.z, av.w};
            float b4[4] = {bv.x, bv.y, bv.z, bv.w};
            #pragma unroll
            for (int i = 0; i < 4; i++)
                #pragma unroll
                for (int j = 0; j < 4; j++)
                    acc[i][j] += a4[i] * b4[j];
        }
    }
    for (int i = 0; i < 4; i++) {
        int r = mtile * 64 + ty * 4 + i;
        h4 hv, lv;
        #pragma unroll
        for (int j = 0; j < 4; j++) {
            float v = acc[i][j] + bin[ntile + tx * 4 + j];
            _Float16 h = (_Float16)v;
            hv[j] = h;
            lv[j] = (_Float16)(v - (float)h);
        }
        size_t off = ((size_t)r * CC + ntile + tx * 4) >> 2;
        ((h4*)feath)[off] = hv;
        ((h4*)featl)[off] = lv;
    }
}

// ===================== stage 2b: row norms from hi/lo =====================
__global__ __launch_bounds__(256) void norm_kernel(
    const _Float16* __restrict__ feath, const _Float16* __restrict__ featl,
    float* __restrict__ normF)
{
    int r = blockIdx.x * 4 + (threadIdx.x >> 6);
    int lane = threadIdx.x & 63;
    h4 hv = ((const h4*)(feath + (size_t)r * CC))[lane];
    h4 lv = ((const h4*)(featl + (size_t)r * CC))[lane];
    float s = 0.f;
    #pragma unroll
    for (int j = 0; j < 4; j++) {
        float x = (float)hv[j] + (float)lv[j];
        s += x * x;
    }
    for (int off = 32; off; off >>= 1) s += __shfl_down(s, off);
    if (lane == 0) normF[r] = s;
}

// ===================== stage 3a: fd argmin via split-f16 MFMA =====================
// grid: x = lt(4), y = kt(4), z = pair(128); block 256 = 4 waves (2x2 of 64x64)
__global__ __launch_bounds__(256) void argmin_mfma(
    const _Float16* __restrict__ feath, const _Float16* __restrict__ featl,
    const float* __restrict__ normF,
    const int* __restrict__ anc, const int* __restrict__ pos, const int* __restrict__ neg,
    float* __restrict__ partv, int* __restrict__ partl, float* __restrict__ partd)
{
    const int lt = blockIdx.x, kt = blockIdx.y, pr = blockIdx.z;
    const int t = pr >> 1, nn2 = pr & 1;
    const int a = anc[t];
    const int bb = nn2 ? neg[t] : pos[t];
    const size_t Abase = ((size_t)a * KK + kt * 128) * CC;
    const size_t Bbase = ((size_t)bb * KK + lt * 128) * CC;
    __shared__ _Float16 Ah[128][40], Al[128][40], Bh[128][40], Bl[128][40];
    __shared__ float rdv[128][2];
    __shared__ int   rdl[128][2];
    __shared__ float rdd[128][2];
    const int tid = threadIdx.x;
    const int w = tid >> 6, lane = tid & 63;
    const int quad = lane >> 4, l16 = lane & 15;
    const int wm = (w >> 1) * 64, wl = (w & 1) * 64;
    const int srow = tid & 127;
    const int smat = tid >> 7;      // 0: stage A, 1: stage B
    const _Float16* gh = (smat ? feath + Bbase : feath + Abase) + (size_t)srow * CC;
    const _Float16* gl = (smat ? featl + Bbase : featl + Abase) + (size_t)srow * CC;
    _Float16 (*sh)[40] = smat ? Bh : Ah;
    _Float16 (*sl)[40] = smat ? Bl : Al;

    f4 acc[4][4];
    #pragma unroll
    for (int i = 0; i < 4; i++)
        #pragma unroll
        for (int j = 0; j < 4; j++)
            acc[i][j] = (f4){0.f, 0.f, 0.f, 0.f};

    for (int k0 = 0; k0 < CC; k0 += 32) {
        __syncthreads();
        {
            const h8* srcH = (const h8*)(gh + k0);
            const h8* srcL = (const h8*)(gl + k0);
            h8 h0 = srcH[0], h1 = srcH[1], h2 = srcH[2], h3 = srcH[3];
            h8 l0 = srcL[0], l1 = srcL[1], l2 = srcL[2], l3 = srcL[3];
            *(h8*)&sh[srow][0]  = h0; *(h8*)&sh[srow][8]  = h1;
            *(h8*)&sh[srow][16] = h2; *(h8*)&sh[srow][24] = h3;
            *(h8*)&sl[srow][0]  = l0; *(h8*)&sl[srow][8]  = l1;
            *(h8*)&sl[srow][16] = l2; *(h8*)&sl[srow][24] = l3;
        }
        __syncthreads();
        h8 afh[4], afl[4], bfh[4], bfl[4];
        #pragma unroll
        for (int i = 0; i < 4; i++) {
            int ra = wm + i * 16 + l16;
            int rb = wl + i * 16 + l16;
            afh[i] = *(const h8*)&Ah[ra][quad * 8];
            afl[i] = *(const h8*)&Al[ra][quad * 8];
            bfh[i] = *(const h8*)&Bh[rb][quad * 8];
            bfl[i] = *(const h8*)&Bl[rb][quad * 8];
        }
        #pragma unroll
        for (int i = 0; i < 4; i++)
            #pragma unroll
            for (int j = 0; j < 4; j++) {
                acc[i][j] = __builtin_amdgcn_mfma_f32_16x16x32_f16(afh[i], bfh[j], acc[i][j], 0, 0, 0);
                acc[i][j] = __builtin_amdgcn_mfma_f32_16x16x32_f16(afh[i], bfl[j], acc[i][j], 0, 0, 0);
                acc[i][j] = __builtin_amdgcn_mfma_f32_16x16x32_f16(afl[i], bfh[j], acc[i][j], 0, 0, 0);
            }
    }
    // epilogue: v = nb - 2*dot, argmin over this block's 128 cols
    float nbj[4];
    #pragma unroll
    for (int j = 0; j < 4; j++)
        nbj[j] = normF[(size_t)bb * KK + lt * 128 + wl + j * 16 + l16];
    #pragma unroll
    for (int i = 0; i < 4; i++) {
        #pragma unroll
        for (int r = 0; r < 4; r++) {
            float bv = INFINITY; int bl = 0; float bd = 0.f;
            #pragma unroll
            for (int j = 0; j < 4; j++) {
                float d = acc[i][j][r];
                float v = nbj[j] - 2.f * d;
                int l = lt * 128 + wl + j * 16 + l16;
                if (v < bv) { bv = v; bl = l; bd = d; }
            }
            #pragma unroll
            for (int off = 1; off < 16; off <<= 1) {
                float ov = __shfl_xor(bv, off);
                int   ol = __shfl_xor(bl, off);
                float od = __shfl_xor(bd, off);
                if (ov < bv || (ov == bv && ol < bl)) { bv = ov; bl = ol; bd = od; }
            }
            if (l16 == 0) {
                int row = wm + i * 16 + quad * 4 + r;
                rdv[row][w & 1] = bv;
                rdl[row][w & 1] = bl;
                rdd[row][w & 1] = bd;
            }
        }
    }
    __syncthreads();
    if (tid < 128) {
        float bv = rdv[tid][0]; int bl = rdl[tid][0]; float bd = rdd[tid][0];
        float v1 = rdv[tid][1]; int l1 = rdl[tid][1];
        if (v1 < bv || (v1 == bv && l1 < bl)) { bv = v1; bl = l1; bd = rdd[tid][1]; }
        size_t idx = (((size_t)pr * 4 + kt) * 128 + tid) * 4 + lt;
        partv[idx] = bv; partl[idx] = bl; partd[idx] = bd;
    }
}

// ===================== stage 3b: merge l-tiles, emit corr + s =====================
__global__ __launch_bounds__(256) void argmin_fin(
    const float* __restrict__ partv, const int* __restrict__ partl,
    const float* __restrict__ partd, const float* __restrict__ normF,
    const int* __restrict__ anc, const int* __restrict__ pos, const int* __restrict__ neg,
    int* __restrict__ corr, float* __restrict__ sbuf)
{
    int g = blockIdx.x * 256 + threadIdx.x;   // pr*512 + kg
    int pr = g >> 9, kg = g & 511;
    int t = pr >> 1, nn2 = pr & 1;
    int a = anc[t];
    int bb = nn2 ? neg[t] : pos[t];
    size_t base = (size_t)g * 4;
    float bv = partv[base]; int bl = partl[base]; float bd = partd[base];
    #pragma unroll
    for (int lt = 1; lt < 4; lt++) {
        float v = partv[base + lt]; int l = partl[base + lt];
        if (v < bv || (v == bv && l < bl)) { bv = v; bl = l; bd = partd[base + lt]; }
    }
    float na = normF[(size_t)a * KK + kg];
    float nb = normF[(size_t)bb * KK + bl];
    float cosv = bd / (sqrtf(na) * sqrtf(nb) + 1e-8f);
    corr[g] = bl;
    sbuf[g] = fmaxf(cosv, 0.f);
}

// ===================== stage 4: geo bitmask =====================
__global__ __launch_bounds__(256) void geo_kernel(
    const float* __restrict__ centk, const int* __restrict__ corr,
    const int* __restrict__ neff,
    const int* __restrict__ anc, const int* __restrict__ pos, const int* __restrict__ neg,
    unsigned* __restrict__ gmask)
{
    const int kt = blockIdx.x;
    const int nn2 = blockIdx.y;
    const int t = blockIdx.z;
    const int a = anc[t];
    const int bb2 = (nn2 == 0) ? pos[t] : neg[t];
    const int nea = neff[a], neb = neff[bb2];
    const int pair = t * 2 + nn2;
    __shared__ __align__(16) float4 ca[512], cq[512];
    for (int i = threadIdx.x; i < KK; i += 256) {
        ca[i] = ((const float4*)centk)[a * KK + i];
        int c = corr[pair * KK + i];
        cq[i] = ((const float4*)centk)[bb2 * KK + c];
    }
    __syncthreads();
    const int k = kt * 256 + threadIdx.x;
    float4 pk = ca[k], qk = cq[k];
    bool rowm = k < nea;
    unsigned* out = gmask + ((size_t)pair * KK + k) * 16;
    for (int w = 0; w < 16; w++) {
        unsigned word = 0;
        #pragma unroll
        for (int bi = 0; bi < 32; bi++) {
            int l = w * 32 + bi;
            float4 pl = ca[l], ql = cq[l];
            float dp2 = pk.w + pl.w - 2.f * (pk.x * pl.x + pk.y * pl.y + pk.z * pl.z);
            float dp = sqrtf(fmaxf(dp2, 0.f) + 1e-12f);
            float dq2 = qk.w + ql.w - 2.f * (qk.x * ql.x + qk.y * ql.y + qk.z * ql.z);
            float dq = sqrtf(fmaxf(dq2, 0.f) + 1e-12f);
            bool g = (fabsf(dp - dq) < 0.5f) && rowm && (l < neb) && (l != k);
            word |= (g ? (1u << bi) : 0u);
        }
        out[w] = word;
    }
}

// ===================== stage 5: power iteration + sort + MLP =====================
__global__ __launch_bounds__(256) void power_kernel(
    const unsigned* __restrict__ gmask, const float* __restrict__ sbuf,
    const float* __restrict__ W1, const float* __restrict__ b1,
    const float* __restrict__ W2, const float* __restrict__ b2,
    float* __restrict__ out)
{
    const int pair = blockIdx.x;
    const int tid = threadIdx.x;
    const int k0 = tid, k1 = tid + 256;
    __shared__ __align__(16) float u[512];
    __shared__ float red[4];
    __shared__ float ev[512];
    unsigned m0[16], m1[16];
    const unsigned* g0 = gmask + ((size_t)pair * KK + k0) * 16;
    const unsigned* g1 = gmask + ((size_t)pair * KK + k1) * 16;
    #pragma unroll
    for (int w = 0; w < 16; w++) { m0[w] = g0[w]; m1[w] = g1[w]; }
    float s0 = sbuf[pair * KK + k0], s1 = sbuf[pair * KK + k1];
    float v0 = 0.044194173824159216f, v1 = v0;
    for (int it = 0; it < 20; it++) {
        u[k0] = s0 * v0; u[k1] = s1 * v1;
        __syncthreads();
        float acc0 = 0.f, acc1 = 0.f;
        #pragma unroll
        for (int w = 0; w < 16; w++) {
            unsigned ma = m0[w], mb = m1[w];
            #pragma unroll
            for (int q = 0; q < 8; q++) {
                float4 uu = *(const float4*)&u[w * 32 + q * 4];
                int base = q * 4;
                if (ma & (1u << (base + 0))) acc0 += uu.x;
                if (ma & (1u << (base + 1))) acc0 += uu.y;
                if (ma & (1u << (base + 2))) acc0 += uu.z;
                if (ma & (1u << (base + 3))) acc0 += uu.w;
                if (mb & (1u << (base + 0))) acc1 += uu.x;
                if (mb & (1u << (base + 1))) acc1 += uu.y;
                if (mb & (1u << (base + 2))) acc1 += uu.z;
                if (mb & (1u << (base + 3))) acc1 += uu.w;
            }
        }
        float w0 = s0 * acc0, w1 = s1 * acc1;
        float t2 = w0 * w0 + w1 * w1;
        for (int off = 32; off; off >>= 1) t2 += __shfl_down(t2, off);
        if ((tid & 63) == 0) red[tid >> 6] = t2;
        __syncthreads();
        float tot = red[0] + red[1] + red[2] + red[3];
        float inv = 1.f / (sqrtf(tot) + 1e-8f);
        v0 = w0 * inv; v1 = w1 * inv;
        __syncthreads();
    }
    ev[k0] = v0; ev[k1] = v1;
    __syncthreads();
    for (int kk = 2; kk <= 512; kk <<= 1) {
        for (int j = kk >> 1; j; j >>= 1) {
            int i = ((tid & ~(j - 1)) << 1) | (tid & (j - 1));
            int p = i | j;
            float x = ev[i], y = ev[p];
            bool up = (i & kk) == 0;
            if (up ? (x < y) : (x > y)) { ev[i] = y; ev[p] = x; }
            __syncthreads();
        }
    }
    float h0 = b1[k0], h1 = b1[k1];
    #pragma unroll 8
    for (int kk = 0; kk < KK; kk++) {
        float e = ev[kk];
        h0 += e * W1[(size_t)kk * KK + k0];
        h1 += e * W1[(size_t)kk * KK + k1];
    }
    h0 = fmaxf(h0, 0.f); h1 = fmaxf(h1, 0.f);
    float term = h0 * W2[k0] + h1 * W2[k1];
    for (int off = 32; off; off >>= 1) term += __shfl_down(term, off);
    __syncthreads();
    if ((tid & 63) == 0) red[tid >> 6] = term;
    __syncthreads();
    if (tid == 0) {
        float sc = red[0] + red[1] + red[2] + red[3] + b2[0];
        out[pair] = 1.f / (1.f + expf(-sc));
        out[NPAIR + pair] = (pair & 1) ? 0.f : 1.f;
    }
}

extern "C" void kernel_launch(void* const* d_in, const int* in_sizes, int n_in,
                              void* d_out, int out_size, void* d_ws, size_t ws_size,
                              hipStream_t stream) {
    (void)in_sizes; (void)n_in; (void)out_size; (void)ws_size;
    const float* rt    = (const float*)d_in[0];
    const float* cents = (const float*)d_in[1];
    const float* attn  = (const float*)d_in[2];
    const float* sas   = (const float*)d_in[3];
    const int* num_rt  = (const int*)d_in[4];
    const int* anc     = (const int*)d_in[5];
    const int* pos     = (const int*)d_in[6];
    const int* neg     = (const int*)d_in[7];
    const float* Win   = (const float*)d_in[8];
    const float* bin   = (const float*)d_in[9];
    const float* W1    = (const float*)d_in[10];
    const float* b1    = (const float*)d_in[11];
    const float* W2    = (const float*)d_in[12];
    const float* b2    = (const float*)d_in[13];

    float* ws = (float*)d_ws;
    _Float16* feath = (_Float16*)ws;
    _Float16* featl = (_Float16*)(ws + 4194304);
    float* normF = ws + 8388608;
    float* centk = ws + 8421376;
    float* sbuf  = ws + 8552448;
    int* topidx  = (int*)(ws + 8617984);
    int* neffp   = (int*)(ws + 8650752);
    int* corr    = (int*)(ws + 8650816);
    unsigned* gmask = (unsigned*)(ws + 8716352);
    float* partv = (float*)(ws + 8716352);
    int*   partl = (int*)(ws + 8716352 + 262144);
    float* partd = (float*)(ws + 8716352 + 524288);
    float* out = (float*)d_out;

    sel_kernel<<<64, 512, 0, stream>>>(attn, cents, sas, num_rt, topidx, neffp, centk);
    feat_kernel<<<dim3(512, 4), 256, 0, stream>>>(rt, topidx, Win, bin, feath, featl);
    norm_kernel<<<8192, 256, 0, stream>>>(feath, featl, normF);
    argmin_mfma<<<dim3(4, 4, 128), 256, 0, stream>>>(feath, featl, normF, anc, pos, neg, partv, partl, partd);
    argmin_fin<<<256, 256, 0, stream>>>(partv, partl, partd, normF, anc, pos, neg, corr, sbuf);
    geo_kernel<<<dim3(2, 2, 64), 256, 0, stream>>>(centk, corr, neffp, anc, pos, neg, gmask);
    power_kernel<<<128, 256, 0, stream>>>(gmask, sbuf, W1, b1, W2, b2, out);
}